// Round 10
// baseline (426.089 us; speedup 1.0000x reference)
//
#include <hip/hip_runtime.h>
#include <cstdint>

// SpikeFP64Sqrt: rows of 64 float pulses (MSB-first fp64 bits) -> sqrt via
// exponent-halving guess + 12 IEEE fp64 Newton iterations -> pulses out.
//
// R9 post-mortem: 16B nt loads + shfl_xor pack in k1 == R7's ballot pack
// (423.7 vs 419.7) -> load width ruled out too. k1 reverted to R7 verbatim.
// R10 attacks kernel2, the remaining suspect for the ~35us over-floor gap:
//   (1) store-issue throttle: old k2 spent ~15 instrs (2 bpermutes + 12
//       extraction VALU) per 16B store; budget for 6.5TB/s is ~24 cyc/store.
//       New k2: 16 offset-immediate dwordx2 word-loads up front (no ds pipe),
//       ~11 VALU/store extraction (per-lane dword select + nib + 4x bfe/cvt).
//   (2) L3 dirty-eviction: plain stores write-allocate 268MB into L3 and
//       evict the poison fill's dirty d_ws lines -> their writebacks land in
//       k2. nt stores skip allocation; poison lines die in-cache at the next
//       fill (same mechanism that made nt LOADS win in R8).

#pragma clang fp contract(off)   // no FMA contraction anywhere (bit-exact fp64)

typedef float f32x4 __attribute__((ext_vector_type(4)));

static constexpr uint64_t kSqrt2Mant = 1865452045155277ULL;
static constexpr uint64_t kNanBits   = 0x7FF8000000000000ULL;
static constexpr uint64_t kInfBits   = 0x7FF0000000000000ULL;
static constexpr uint64_t kMantMask  = 0xFFFFFFFFFFFFFULL;

// ---------------- kernel 1 (R7 verbatim): pulses -> u64 -> sqrt -> words ---
__global__ __launch_bounds__(256) void spike_sqrt_pack_kernel(
    const float* __restrict__ x, uint64_t* __restrict__ w, int rows) {
  const int lane   = threadIdx.x & 63;
  const int waveId = (int)blockIdx.x * 4 + (threadIdx.x >> 6);
  const long long waveRow0 = (long long)waveId * 64;
  const int col = lane ^ 63;   // lane j reads pulse (63-j): ballot bit j == MSB-first bit j

  uint64_t u = 0;
  const bool fullWave = (waveRow0 + 64) <= (long long)rows;
  if (fullWave) {
    const float* base = x + waveRow0 * 64 + col;
#pragma unroll
    for (int b = 0; b < 2; ++b) {
      float v[32];
#pragma unroll
      for (int k = 0; k < 32; ++k)   // 32 nt loads in flight (read-once stream)
        v[k] = __builtin_nontemporal_load(base + (size_t)(b * 32 + k) * 64);
#pragma unroll
      for (int k = 0; k < 32; ++k) {
        unsigned long long m = __ballot(v[k] > 0.5f);
        if (lane == b * 32 + k) u = m;
      }
    }
  } else {
#pragma unroll 4
    for (int rr = 0; rr < 64; ++rr) {
      const long long row = waveRow0 + rr;
      float v = (row < (long long)rows) ? x[row * 64 + col] : 0.0f;
      unsigned long long m = __ballot(v > 0.5f);
      if (lane == rr) u = m;
    }
  }

  // ---- per-lane fp64 sqrt, bit-exact vs reference ----
  const double f = __longlong_as_double((long long)u);

  const int e_x    = (int)((u >> 52) & 0x7FF);
  const int e_real = e_x - 1023;                       // 11-bit two's complement
  const long long e_half = ((long long)e_real) >> 1;   // arithmetic shift = floor/2
  const uint64_t mant = ((e_real & 1) != 0) ? kSqrt2Mant : 0ULL;
  const uint64_t ybits = (((uint64_t)(e_half + 1023)) << 52) | mant;
  double y = __longlong_as_double((long long)ybits);

#pragma unroll
  for (int it = 0; it < 12; ++it) {
    y = 0.5 * (y + f / y);                             // IEEE fp64, no contraction
  }

  uint64_t r = (uint64_t)__double_as_longlong(y);
  const bool is_neg    = (u >> 63) != 0;
  const bool m_any     = (u & kMantMask) != 0;
  const bool e_all_one = (e_x == 0x7FF);
  const bool e_is_zero = (e_x == 0);
  if (is_neg) r = kNanBits;                            // same override order as ref
  if (e_all_one && m_any) r = kNanBits;
  if (e_all_one && !m_any && !is_neg) r = kInfBits;
  if (e_is_zero && !m_any) r = 0ULL;

  const long long myRow = waveRow0 + lane;
  if (myRow < (long long)rows) w[myRow] = r;           // coalesced dwordx2, 512B/wave
}

// -------- kernel 2: words -> pulses; lean extraction + nt store stream -----
__global__ __launch_bounds__(256) void spike_unpack_kernel(
    const uint64_t* __restrict__ w, float* __restrict__ out, int rows) {
  const int lane   = threadIdx.x & 63;
  const int waveId = (int)blockIdx.x * 4 + (threadIdx.x >> 6);
  const long long waveRow0 = (long long)waveId * 64;
  const int grp = lane >> 4;            // row within each 4-row store group
  const int c0  = (lane & 15) * 4;      // pulse column of o.x

  if ((waveRow0 + 64) <= (long long)rows) {
    // 16 independent word loads, offset-immediate, issued back-to-back
    const uint64_t* wbase = w + waveRow0 + grp;
    uint64_t ld[16];
#pragma unroll
    for (int t = 0; t < 16; ++t) ld[t] = wbase[4 * t];

    const bool hiSel = (lane & 15) < 8;           // bits 63-c0.. live in hi dword
    const int  sh    = (60 - c0) & 31;            // nib start within that dword
    float* obase = out + (waveRow0 + grp) * 64 + c0;
#pragma unroll
    for (int t = 0; t < 16; ++t) {
      const uint32_t lo  = (uint32_t)ld[t];
      const uint32_t hi  = (uint32_t)(ld[t] >> 32);
      const uint32_t sel = hiSel ? hi : lo;       // 1 cndmask
      const uint32_t nib = (sel >> sh) & 0xFu;    // pulses c0..c0+3, MSB first
      f32x4 o;
      o.x = (float)((nib >> 3) & 1u);             // bfe + cvt each
      o.y = (float)((nib >> 2) & 1u);
      o.z = (float)((nib >> 1) & 1u);
      o.w = (float)(nib & 1u);
      __builtin_nontemporal_store(o, (f32x4*)(obase + (size_t)t * 256));
    }
  } else {
    // tail fallback (unused at this size)
    const long long myRow = waveRow0 + lane;
    const uint64_t r = (myRow < (long long)rows) ? w[myRow] : 0ULL;
    const long long rl = (long long)r;
#pragma unroll 4
    for (int t = 0; t < 16; ++t) {
      const int srcRow = 4 * t + grp;
      const uint64_t b = (uint64_t)__shfl(rl, srcRow, 64);
      f32x4 o;
      o.x = (float)((b >> (63 - c0)) & 1ULL);
      o.y = (float)((b >> (62 - c0)) & 1ULL);
      o.z = (float)((b >> (61 - c0)) & 1ULL);
      o.w = (float)((b >> (60 - c0)) & 1ULL);
      const long long row = waveRow0 + srcRow;
      if (row < (long long)rows) {
        *reinterpret_cast<f32x4*>(out + row * 64 + c0) = o;
      }
    }
  }
}

extern "C" void kernel_launch(void* const* d_in, const int* in_sizes, int n_in,
                              void* d_out, int out_size, void* d_ws, size_t ws_size,
                              hipStream_t stream) {
  const float* x = (const float*)d_in[0];
  float* out = (float*)d_out;
  uint64_t* words = (uint64_t*)d_ws;                   // rows*8 bytes (8MB) scratch
  const int rows = in_sizes[0] / 64;                   // 64 pulses per fp64
  const int grid = (rows + 255) / 256;                 // 4 waves * 64 rows
  spike_sqrt_pack_kernel<<<grid, 256, 0, stream>>>(x, words, rows);
  spike_unpack_kernel<<<grid, 256, 0, stream>>>(words, out, rows);
}